// Round 2
// baseline (314.998 us; speedup 1.0000x reference)
//
#include <hip/hip_runtime.h>
#include <hip/hip_bf16.h>

#define NB 262144   // batch
#define KD 512      // in_dim
#define ED 10000    // embed_dim

typedef __attribute__((ext_vector_type(8))) short s8v;
typedef __attribute__((ext_vector_type(4))) float f4v;

typedef __attribute__((address_space(1))) const unsigned int gu32_t;
typedef __attribute__((address_space(3))) unsigned int lu32_t;

__device__ __forceinline__ short f2bf(float f) {
  union { __hip_bfloat16 h; short s; } u;
  u.h = __float2bfloat16(f);
  return u.s;
}

// ---------------- prep: pack [W_logvar; W_mean] -> bf16 [256][512] ----------------
__global__ void prep_w(const float* __restrict__ Wlv, const float* __restrict__ Wmu,
                       unsigned short* __restrict__ wbf) {
  int i = blockIdx.x * 256 + threadIdx.x;          // [0, 131072)
  int row = i >> 9, col = i & 511;
  float v = (row < 128) ? Wlv[(row << 9) | col] : Wmu[((row - 128) << 9) | col];
  union { __hip_bfloat16 h; unsigned short s; } u;
  u.h = __float2bfloat16(v);
  wbf[i] = u.s;
}

// ---------------- prep: embT[v][l] = W_embed[l][v] + b_embed[l] (tiled transpose) ----------------
__global__ void prep_embT(const float* __restrict__ We, const float* __restrict__ be,
                          float* __restrict__ embT) {
  __shared__ float t[32][129];
  const int v0 = blockIdx.x << 5;
#pragma unroll
  for (int j = 0; j < 16; ++j) {
    int idx = j * 256 + threadIdx.x;     // [0, 4096)
    int l = idx >> 5, vi = idx & 31;
    int v = v0 + vi;
    t[vi][l] = (v < ED) ? We[(size_t)l * ED + v] : 0.f;   // coalesced: 32 consecutive v per l
  }
  __syncthreads();
#pragma unroll
  for (int j = 0; j < 16; ++j) {
    int idx = j * 256 + threadIdx.x;
    int v = idx >> 7, l = idx & 127;
    if (v0 + v < ED)
      embT[(size_t)(v0 + v) * 128 + l] = t[v][l] + be[l];  // coalesced rows of 512B
  }
}

// ---------------- main GEMM: logvar & mean heads ----------------
// x fp32 [B][512]; wbf bf16 [256][512].  Tile 128x256, BK=32, 16 K-steps.
// LDS: A fp32 [128][32] x2 (32KB) + B bf16 [256][32] x2 (32KB) = 64KB, double-buffered.
// T3 2-phase: STAGE(t+1) -> compute(t) -> syncthreads (drain+barrier).
__global__ __launch_bounds__(512, 4) void gemm_heads(
    const float* __restrict__ x, const unsigned short* __restrict__ wbf,
    const float* __restrict__ blv, const float* __restrict__ bmu,
    float* __restrict__ out) {
  __shared__ char lds[65536];
  const int tid  = threadIdx.x;
  const int lane = tid & 63;
  const int wid  = tid >> 6;
  const int gm   = blockIdx.x << 7;
  const int wm   = wid >> 2;   // 0..1 (M)
  const int wn   = wid & 3;    // 0..3 (N)
  const float* xblk = x + ((size_t)gm << 9);

  // --- staging descriptors: 2 A-chunks + 2 B-chunks (16B each) per thread ---
  // A: chunk c in [0,1024): row=c>>3 (128B row = 8 chunks), src 32B-group ^= (row&3)
  // B: chunk c in [0,1024): row=c>>2 (64B row = 4 chunks),  src 16B-chunk ^= ((row>>1)&3)
  unsigned aSrc[2], aDst[2], bSrc[2], bDst[2];
#pragma unroll
  for (int s = 0; s < 2; ++s) {
    int c = tid + (s << 9);
    { int row = c >> 3, q = c & 7;
      int qp = q ^ ((row & 3) << 1);
      aSrc[s] = (unsigned)(row << 9) + (unsigned)(qp << 2);   // float elems (+ke)
      aDst[s] = (unsigned)(c << 4); }
    { int row = c >> 2, q = c & 3;
      int qp = q ^ ((row >> 1) & 3);
      bSrc[s] = (unsigned)(row << 9) + (unsigned)(qp << 3);   // bf16 elems (+ke)
      bDst[s] = 32768u + (unsigned)(c << 4); }
  }

  // --- fragment-read offsets (buf0; +16384 toggles buffer) ---
  unsigned offA[4], offB[4];
#pragma unroll
  for (int t4 = 0; t4 < 4; ++t4) {
    { int row = (wm << 6) + (t4 << 4) + (lane & 15);
      int q = ((lane >> 4) << 1) ^ ((row & 3) << 1);          // 16B-chunk idx, b=0
      offA[t4] = (unsigned)(row << 7) + (unsigned)(q << 4); }
    { int row = (wn << 6) + (t4 << 4) + (lane & 15);
      int q = (lane >> 4) ^ ((row >> 1) & 3);
      offB[t4] = 32768u + (unsigned)(row << 6) + (unsigned)(q << 4); }
  }

  f4v acc[4][4];
#pragma unroll
  for (int i = 0; i < 4; ++i)
#pragma unroll
    for (int j = 0; j < 4; ++j) acc[i][j] = (f4v)0.f;

  // prologue: stage tile 0 into buf0
#pragma unroll
  for (int s = 0; s < 2; ++s) {
    __builtin_amdgcn_global_load_lds((const gu32_t*)(xblk + aSrc[s]),
                                     (lu32_t*)(lds + aDst[s]), 16, 0, 0);
    __builtin_amdgcn_global_load_lds((const gu32_t*)(wbf + bSrc[s]),
                                     (lu32_t*)(lds + bDst[s]), 16, 0, 0);
  }
  __syncthreads();

  for (int t = 0; t < 16; ++t) {
    const unsigned db = (unsigned)((t & 1) << 14);
    if (t < 15) {   // prefetch tile t+1 into the other buffer; streams during compute
      const int ke = (t + 1) << 5;
      const unsigned db2 = (unsigned)(((t + 1) & 1) << 14);
#pragma unroll
      for (int s = 0; s < 2; ++s) {
        __builtin_amdgcn_global_load_lds((const gu32_t*)(xblk + aSrc[s] + ke),
                                         (lu32_t*)(lds + aDst[s] + db2), 16, 0, 0);
        __builtin_amdgcn_global_load_lds((const gu32_t*)(wbf + bSrc[s] + ke),
                                         (lu32_t*)(lds + bDst[s] + db2), 16, 0, 0);
      }
    }
    // compute tile t from buf (t&1)
    s8v bfr[4];
#pragma unroll
    for (int nt = 0; nt < 4; ++nt)
      bfr[nt] = *(const s8v*)(lds + offB[nt] + db);
#pragma unroll
    for (int mt = 0; mt < 4; ++mt) {
      const char* pa = lds + offA[mt] + db;
      float4 a0 = *(const float4*)(pa);
      float4 a1 = *(const float4*)(pa + 16);
      s8v af;
      af[0] = f2bf(a0.x); af[1] = f2bf(a0.y); af[2] = f2bf(a0.z); af[3] = f2bf(a0.w);
      af[4] = f2bf(a1.x); af[5] = f2bf(a1.y); af[6] = f2bf(a1.z); af[7] = f2bf(a1.w);
#pragma unroll
      for (int nt = 0; nt < 4; ++nt)
        acc[mt][nt] = __builtin_amdgcn_mfma_f32_16x16x32_bf16(af, bfr[nt], acc[mt][nt], 0, 0, 0);
    }
    __syncthreads();   // drains prefetch (vmcnt 0) + lds reads, syncs buffers
  }

  // epilogue: C/D layout col=lane&15, row=(lane>>4)*4+r
  const int col16 = lane & 15;
  const int rsub  = (lane >> 4) << 2;
#pragma unroll
  for (int nt = 0; nt < 4; ++nt) {
    int col = (wn << 6) + (nt << 4) + col16;
    float bias = (col < 128) ? blv[col] : bmu[col - 128];
    float* ob = (col < 128) ? (out + col)
                            : (out + ((size_t)NB << 7) + (col - 128));
#pragma unroll
    for (int mt = 0; mt < 4; ++mt) {
      int row0 = gm + (wm << 6) + (mt << 4) + rsub;
#pragma unroll
      for (int r = 0; r < 4; ++r)
        ob[(size_t)(row0 + r) << 7] = acc[mt][nt][r] + bias;
    }
  }
}

// ---------------- embed: coalesced row gather from embT ----------------
__global__ void embed_fast(const int* __restrict__ y, const float* __restrict__ embT,
                           float* __restrict__ out3) {
  unsigned t = blockIdx.x * 256 + threadIdx.x;   // [0, NB*32)
  int b  = t >> 5;
  int l4 = (t & 31) << 2;
  int v  = y[b];
  float4 s = *(const float4*)(embT + (size_t)v * 128 + l4);
  *(float4*)(out3 + ((size_t)b << 7) + l4) = s;
}

// ---------------- fallbacks (only if ws_size too small) ----------------
__global__ void gemm_naive(const float* __restrict__ x,
                           const float* __restrict__ Wlv, const float* __restrict__ blv,
                           const float* __restrict__ Wmu, const float* __restrict__ bmu,
                           float* __restrict__ out) {
  __shared__ float xr[512];
  int b = blockIdx.x;
  for (int i = threadIdx.x; i < 512; i += 256) xr[i] = x[(size_t)b * 512 + i];
  __syncthreads();
  int c = threadIdx.x;
  const float* w = (c < 128) ? (Wlv + c * 512) : (Wmu + (c - 128) * 512);
  float s = 0.f;
  for (int k = 0; k < 512; ++k) s += xr[k] * w[k];
  s += (c < 128) ? blv[c] : bmu[c - 128];
  float* o = (c < 128) ? (out + (size_t)b * 128 + c)
                       : (out + ((size_t)NB << 7) + (size_t)b * 128 + (c - 128));
  *o = s;
}

__global__ void embed_direct(const int* __restrict__ y, const float* __restrict__ We,
                             const float* __restrict__ be, float* __restrict__ out3) {
  size_t t = (size_t)blockIdx.x * 256 + threadIdx.x;
  int b = (int)(t >> 7), l = (int)(t & 127);
  out3[t] = We[(size_t)l * ED + y[b]] + be[l];
}

extern "C" void kernel_launch(void* const* d_in, const int* in_sizes, int n_in,
                              void* d_out, int out_size, void* d_ws, size_t ws_size,
                              hipStream_t stream) {
  const float* x   = (const float*)d_in[0];
  const int*   y   = (const int*)d_in[1];
  const float* Wlv = (const float*)d_in[2];
  const float* blv = (const float*)d_in[3];
  const float* Wmu = (const float*)d_in[4];
  const float* bmu = (const float*)d_in[5];
  const float* We  = (const float*)d_in[6];
  const float* be  = (const float*)d_in[7];
  float* out  = (float*)d_out;
  float* out3 = out + ((size_t)NB << 8);   // after logvar+mean (2*B*128)

  const size_t needW = 256 * 512 * sizeof(unsigned short);          // 256 KB
  const size_t needE = needW + (size_t)ED * 128 * sizeof(float);    // + 5.12 MB
  unsigned short* wbf = (unsigned short*)d_ws;
  float* embT = (float*)((char*)d_ws + needW);

  if (ws_size >= needW) {
    prep_w<<<512, 256, 0, stream>>>(Wlv, Wmu, wbf);
    gemm_heads<<<NB / 128, 512, 0, stream>>>(x, wbf, blv, bmu, out);
  } else {
    gemm_naive<<<NB, 256, 0, stream>>>(x, Wlv, blv, Wmu, bmu, out);
  }

  if (ws_size >= needE) {
    prep_embT<<<(ED + 31) / 32, 256, 0, stream>>>(We, be, embT);
    embed_fast<<<NB * 32 / 256, 256, 0, stream>>>(y, embT, out3);
  } else {
    embed_direct<<<NB * 128 / 256, 256, 0, stream>>>(y, We, be, out3);
  }
}